// Round 4
// baseline (185.323 us; speedup 1.0000x reference)
//
#include <hip/hip_runtime.h>

// Problem constants
#define BATCH   32
#define CIN     256
#define COUT    64
#define HW      1024          // 32*32
#define NE      1024          // codebook size
#define ED      64            // code dim
#define NROW    32768         // BATCH*COUT*HW/ED
#define ZTOT    2097152       // BATCH*COUT*HW

// d_out layout (floats): z_q_st[ZTOT], loss[1], sampled[32768], min_idx[32768]
#define OFF_LOSS 2097152
#define OFF_SAMP 2097153
#define OFF_IDX  2129921

// LDS strides (floats)
#define CXSTR 132   // conv Xs [64 c][128 px]
#define CWSTR 68    // conv Ws [64 c][64 o]
#define ZROWS 68    // dist zs [64 row][64 k + 4 pad]   row-major
#define EROWS 36    // dist es [256 code][32 k + 4 pad] row-major, half-K slice

// ---------------------------------------------------------------------------
// k_pre: one launch fusing (a) sampled zeroing + counter zero, (b) contrastive
// partials with block-local inv-norms, (c) enorm for k_dist, (d) the 1x1 conv.
// blocks 0..127   : zero out_samp (block 0 also zeroes the done-counter)
// blocks 128..143 : contrast partial
// blocks 144..147 : enorm
// blocks 148..403 : conv, 128px x 64out tile (8px x 4o per thread)
__global__ __launch_bounds__(256, 2) void k_pre(const float* __restrict__ x,
                                                const float* __restrict__ w,
                                                const float* __restrict__ bias,
                                                float* __restrict__ z,
                                                const float* __restrict__ emb,
                                                float* __restrict__ out_samp,
                                                float* __restrict__ enorm,
                                                float* __restrict__ cpart,
                                                unsigned int* __restrict__ counter) {
    __shared__ float SH[64 * CXSTR + 64 * CWSTR];   // 51.2 KB, aliased per branch
    int bx = blockIdx.x;
    int t  = threadIdx.x;

    if (bx < 128) {                       // ---- zero sampled
        if (bx == 0 && t == 0) *counter = 0u;
        out_samp[bx * 256 + t] = 0.0f;
        return;
    }
    if (bx < 144) {                       // ---- contrast partial (16 blocks)
        float* invl = SH;                 // [64]
        float* S    = SH + 64;            // [256]
        int b2 = bx - 128;
        int i0 = b2 * 64;
        if (t < 64) {
            const float* e = emb + (size_t)(i0 + t) * ED;
            float r8[8];
            #pragma unroll
            for (int s = 0; s < 8; s++) { float xx = e[s]; r8[s] = xx * xx; }
            #pragma unroll
            for (int m = 1; m < 8; m++) {
                #pragma unroll
                for (int s = 0; s < 8; s++) { float xx = e[8 * m + s]; r8[s] += xx * xx; }
            }
            float en = ((r8[0] + r8[1]) + (r8[2] + r8[3])) + ((r8[4] + r8[5]) + (r8[6] + r8[7]));
            invl[t] = 1.0f / sqrtf(en);
        }
        __syncthreads();
        int d = t & 63, q = t >> 6;
        float s = 0.0f;
        #pragma unroll
        for (int m = 0; m < 16; m++) {
            int il = q + 4 * m;
            s = fmaf(emb[(size_t)(i0 + il) * ED + d], invl[il], s);
        }
        S[t] = s;
        __syncthreads();
        if (t < 64)
            cpart[b2 * 64 + t] = (S[t] + S[t + 64]) + (S[t + 128] + S[t + 192]);
        return;
    }
    if (bx < 148) {                       // ---- enorm (4 blocks)
        int j = (bx - 144) * 256 + t;     // 0..1023
        const float* e = emb + (size_t)j * ED;
        float r8[8];
        #pragma unroll
        for (int s = 0; s < 8; s++) { float xx = e[s]; r8[s] = xx * xx; }
        #pragma unroll
        for (int m = 1; m < 8; m++) {
            #pragma unroll
            for (int s = 0; s < 8; s++) { float xx = e[8 * m + s]; r8[s] += xx * xx; }
        }
        enorm[j] = ((r8[0] + r8[1]) + (r8[2] + r8[3])) + ((r8[4] + r8[5]) + (r8[6] + r8[7]));
        return;
    }

    // ---- conv: block covers batch b, 128-px tile, all 64 outputs
    float* Xs = SH;                       // [64 c][CXSTR]
    float* Ws = SH + 64 * CXSTR;          // [64 c][CWSTR]
    int cbx = bx - 148;
    int b   = cbx >> 3;                   // 0..31
    int p0  = (cbx & 7) * 128;            // 0..896
    int pg  = t & 15;                     // px: 4*pg+i and 64+4*pg+i
    int og  = t >> 4;                     // o : 4*og+j
    float acc[8][4];
    #pragma unroll
    for (int i = 0; i < 8; i++)
        #pragma unroll
        for (int j = 0; j < 4; j++) acc[i][j] = 0.0f;

    for (int c0 = 0; c0 < CIN; c0 += 64) {
        __syncthreads();
        {
            int u = t & 31, cc = t >> 5;          // Xs stage: 64c x 128px
            #pragma unroll
            for (int m = 0; m < 8; m++) {
                int c = cc + 8 * m;
                float4 v = *(const float4*)&x[(size_t)(b * CIN + c0 + c) * HW + p0 + 4 * u];
                *(float4*)&Xs[c * CXSTR + 4 * u] = v;
            }
            int u2 = t & 15, o2 = t >> 4;         // Ws stage (transposed)
            #pragma unroll
            for (int m = 0; m < 4; m++) {
                int o = o2 + 16 * m;
                float4 v = *(const float4*)&w[o * CIN + c0 + 4 * u2];
                Ws[(4 * u2 + 0) * CWSTR + o] = v.x;
                Ws[(4 * u2 + 1) * CWSTR + o] = v.y;
                Ws[(4 * u2 + 2) * CWSTR + o] = v.z;
                Ws[(4 * u2 + 3) * CWSTR + o] = v.w;
            }
        }
        __syncthreads();
        #pragma unroll 4
        for (int k = 0; k < 64; k++) {
            float4 xa4 = *(const float4*)&Xs[k * CXSTR + 4 * pg];
            float4 xb4 = *(const float4*)&Xs[k * CXSTR + 64 + 4 * pg];
            float4 wv4 = *(const float4*)&Ws[k * CWSTR + 4 * og];
            float xa[8] = {xa4.x, xa4.y, xa4.z, xa4.w, xb4.x, xb4.y, xb4.z, xb4.w};
            float wb[4] = {wv4.x, wv4.y, wv4.z, wv4.w};
            #pragma unroll
            for (int i = 0; i < 8; i++)
                #pragma unroll
                for (int j = 0; j < 4; j++)
                    acc[i][j] = fmaf(xa[i], wb[j], acc[i][j]);
        }
    }
    #pragma unroll
    for (int j = 0; j < 4; j++) {
        int o = 4 * og + j;
        float bv = bias[o];
        float4 lo, hi;
        lo.x = acc[0][j] + bv; lo.y = acc[1][j] + bv;
        lo.z = acc[2][j] + bv; lo.w = acc[3][j] + bv;
        hi.x = acc[4][j] + bv; hi.y = acc[5][j] + bv;
        hi.z = acc[6][j] + bv; hi.w = acc[7][j] + bv;
        *(float4*)&z[(size_t)(b * COUT + o) * HW + p0 + 4 * pg]      = lo;
        *(float4*)&z[(size_t)(b * COUT + o) * HW + p0 + 64 + 4 * pg] = hi;
    }
}

// ---------------------------------------------------------------------------
// k_dist v4: 512 blocks x 256 threads (v0's proven 8 waves/CU), 64 rows/block,
// tile 8x8 (1 B/FMA LDS, vs v0's 1.5). LDS fits 2 blocks/CU by staging emb in
// HALF-K slices: es[256 codes][32 k] row-major (36.9 KB) + zs[64 rows][64 k]
// row-major (17.4 KB). Row-major both sides: staging is pure coalesced float4
// copy (no transposes), inner loop reads both operands along k as float4.
// Per (row,code) the dot is one k-ascending fmaf chain across both k-halves
// -> bit-identical distances; argmin scan order (chunk asc, j asc) matches
// global ascending code index per thread; cross-thread tie-break jj<bj.
// Last block folds in the loss reduction (same trees as R0).
__global__ __launch_bounds__(256, 2) void k_dist(const float* __restrict__ z,
                                                 const float* __restrict__ emb,
                                                 const float* __restrict__ enorm,
                                                 const float* __restrict__ cpart,
                                                 float* __restrict__ out_idx,
                                                 float* __restrict__ out_samp,
                                                 float* __restrict__ out_zq,
                                                 float* __restrict__ ssep,
                                                 float* __restrict__ out_loss,
                                                 unsigned int* __restrict__ counter) {
    __shared__ float zs[64 * ZROWS];      // [row][k]      17.4 KB
    __shared__ float es[256 * EROWS];     // [code][k/2]   36.9 KB (+ scratch overlay)
    __shared__ float zn_s[64];
    __shared__ float en_s[256];
    __shared__ float warr[4];
    __shared__ int   lastflag;
    __shared__ float CS;
    float* redd_s = es;                   // [32][64] floats (post-compute overlay)
    int*   redj_s = (int*)(es + 2048);    // [32][64] ints
    int*   bj_s   = (int*)(es + 4096);    // [128]
    int t = threadIdx.x;
    int row0 = blockIdx.x * 64;
    int rg = t >> 5;     // rows  rg + 8*i   (i=0..7)
    int cg = t & 31;     // codes cg + 32*j  (j=0..7, local in 256-chunk)

    // stage zs row-major: coalesced float4 copy (4 per thread)
    {
        int k4 = t & 15, rr = t >> 4;     // 16 rows per pass
        #pragma unroll
        for (int m = 0; m < 4; m++) {
            int r = rr + 16 * m;
            float4 v = *(const float4*)&z[(size_t)(row0 + r) * ED + 4 * k4];
            *(float4*)&zs[r * ZROWS + 4 * k4] = v;
        }
    }
    __syncthreads();
    // zn: numpy-pairwise sum of squares per row (row-major: natural reads)
    if (t < 64) {
        const float* zr = &zs[t * ZROWS];
        float r8[8];
        #pragma unroll
        for (int s = 0; s < 8; s++) { float xx = zr[s]; r8[s] = xx * xx; }
        #pragma unroll
        for (int m = 1; m < 8; m++) {
            #pragma unroll
            for (int s = 0; s < 8; s++) { float xx = zr[8 * m + s]; r8[s] += xx * xx; }
        }
        zn_s[t] = ((r8[0] + r8[1]) + (r8[2] + r8[3])) + ((r8[4] + r8[5]) + (r8[6] + r8[7]));
    }

    float bestd[8];
    int   bestj[8];
    #pragma unroll
    for (int i = 0; i < 8; i++) { bestd[i] = __builtin_huge_valf(); bestj[i] = 0; }

    for (int ch = 0; ch < 4; ch++) {
        int c0 = ch * 256;
        float acc[8][8];
        #pragma unroll
        for (int i = 0; i < 8; i++)
            #pragma unroll
            for (int j = 0; j < 8; j++) acc[i][j] = 0.0f;

        for (int kh = 0; kh < 2; kh++) {
            __syncthreads();   // protect es/en_s from prior readers (covers zn_s at first iter)
            {
                int k4 = t & 7, cc = t >> 3;      // 32 codes per pass, 8 passes
                #pragma unroll
                for (int m = 0; m < 8; m++) {
                    int c = cc + 32 * m;
                    float4 v = *(const float4*)&emb[(size_t)(c0 + c) * ED + kh * 32 + 4 * k4];
                    *(float4*)&es[c * EROWS + 4 * k4] = v;
                }
                if (kh == 0 && t < 64) {
                    float4 ev = *(const float4*)&enorm[c0 + 4 * t];
                    *(float4*)&en_s[4 * t] = ev;
                }
            }
            __syncthreads();

            int kb = kh * 32;
            #pragma unroll 2
            for (int ks = 0; ks < 8; ks++) {
                float4 za[8], eb[8];
                #pragma unroll
                for (int i = 0; i < 8; i++)
                    za[i] = *(const float4*)&zs[(rg + 8 * i) * ZROWS + kb + 4 * ks];
                #pragma unroll
                for (int j = 0; j < 8; j++)
                    eb[j] = *(const float4*)&es[(cg + 32 * j) * EROWS + 4 * ks];
                #pragma unroll
                for (int i = 0; i < 8; i++)
                    #pragma unroll
                    for (int j = 0; j < 8; j++) {
                        acc[i][j] = fmaf(za[i].x, eb[j].x, acc[i][j]);
                        acc[i][j] = fmaf(za[i].y, eb[j].y, acc[i][j]);
                        acc[i][j] = fmaf(za[i].z, eb[j].z, acc[i][j]);
                        acc[i][j] = fmaf(za[i].w, eb[j].w, acc[i][j]);
                    }
            }
        }

        // epilogue: d = fl(fl(zn + en) - 2*dot); strict < keeps first index
        #pragma unroll
        for (int i = 0; i < 8; i++) {
            float zn = zn_s[rg + 8 * i];
            #pragma unroll
            for (int j = 0; j < 8; j++) {
                int cl = cg + 32 * j;
                float A = zn + en_s[cl];
                float D = A - 2.0f * acc[i][j];
                if (D < bestd[i]) { bestd[i] = D; bestj[i] = c0 + cl; }
            }
        }
    }

    __syncthreads();   // es dead; safe to overlay argmin scratch
    #pragma unroll
    for (int i = 0; i < 8; i++) {
        int rl = rg + 8 * i;
        redd_s[cg * 64 + rl] = bestd[i];
        redj_s[cg * 64 + rl] = bestj[i];
    }
    __syncthreads();
    if (t < 64) {
        float bd = __builtin_huge_valf();
        int   bj = 0x7fffffff;
        #pragma unroll
        for (int c = 0; c < 32; c++) {
            float dd = redd_s[c * 64 + t];
            int   jj = redj_s[c * 64 + t];
            if (dd < bd || (dd == bd && jj < bj)) { bd = dd; bj = jj; }
        }
        int rowg = row0 + t;
        bj_s[t]       = bj;
        out_idx[rowg] = (float)bj;              // min_idx as float
        atomicExch(&out_samp[bj], 1.0f);        // scattered, low contention
    }
    __syncthreads();

    // Fused STE epilogue: z from zs (bit-exact), emb gather, SSE partial.
    // thread t: row r = t&63, k-range [16*kq, 16*kq+16)
    {
        int r  = t & 63;
        int kq = t >> 6;
        int bj = bj_s[r];
        const float* er = emb + (size_t)bj * ED + kq * 16;
        const float* zr = &zs[r * ZROWS + kq * 16];
        float sq = 0.0f;
        #pragma unroll
        for (int m = 0; m < 4; m++) {
            float4 ev = *(const float4*)&er[4 * m];
            float4 zv = *(const float4*)&zr[4 * m];
            float d0 = ev.x - zv.x, d1 = ev.y - zv.y, d2 = ev.z - zv.z, d3 = ev.w - zv.w;
            float4 o4;
            o4.x = zv.x + d0; o4.y = zv.y + d1; o4.z = zv.z + d2; o4.w = zv.w + d3;
            *(float4*)&out_zq[(size_t)(row0 + r) * ED + kq * 16 + 4 * m] = o4;
            sq += d0 * d0; sq += d1 * d1; sq += d2 * d2; sq += d3 * d3;
        }
        #pragma unroll
        for (int off = 32; off > 0; off >>= 1) sq += __shfl_down(sq, off, 64);
        if ((t & 63) == 0) warr[t >> 6] = sq;
    }
    __syncthreads();

    // Last-block loss reduction: release-fence + counter (512 blocks).
    if (t == 0) {
        ssep[blockIdx.x] = (warr[0] + warr[1]) + (warr[2] + warr[3]);
        __threadfence();                       // make ssep visible device-wide
        unsigned int old = atomicAdd(counter, 1u);
        lastflag = (old == 511u) ? 1 : 0;
    }
    __syncthreads();
    if (lastflag) {
        __threadfence();                       // acquire: see all blocks' ssep
        double* SD = (double*)es;              // es scratch dead; 2 KB
        const volatile float* sv = (const volatile float*)ssep;
        SD[t] = (double)sv[t] + (double)sv[t + 256];
        __syncthreads();
        #pragma unroll
        for (int off = 128; off > 0; off >>= 1) {
            if (t < off) SD[t] += SD[t + off];
            __syncthreads();
        }
        if (t < 64) {
            float v = 0.0f;
            #pragma unroll
            for (int m = 0; m < 16; m++) v += cpart[m * 64 + t];
            float sq = v * v;
            #pragma unroll
            for (int off = 32; off > 0; off >>= 1) sq += __shfl_down(sq, off, 64);
            if (t == 0) CS = sq / (1024.0f * 1024.0f);
        }
        __syncthreads();
        if (t == 0) {
            float m = (float)(SD[0] / (double)ZTOT);
            float loss = m + 0.25f * m;        // LEGACY: mse + BETA*mse
            out_loss[0] = loss + CS;
        }
    }
}

// ---------------------------------------------------------------------------
extern "C" void kernel_launch(void* const* d_in, const int* in_sizes, int n_in,
                              void* d_out, int out_size, void* d_ws, size_t ws_size,
                              hipStream_t stream) {
    (void)in_sizes; (void)n_in; (void)out_size; (void)ws_size;
    const float* z_     = (const float*)d_in[0];
    const float* conv_w = (const float*)d_in[1];
    const float* conv_b = (const float*)d_in[2];
    const float* emb    = (const float*)d_in[3];

    float* out      = (float*)d_out;
    float* out_zq   = out;
    float* out_loss = out + OFF_LOSS;
    float* out_samp = out + OFF_SAMP;
    float* out_idx  = out + OFF_IDX;

    char*  ws       = (char*)d_ws;
    float* wz       = (float*)ws;                         // 2M floats (8 MB)
    float* enorm    = (float*)(ws + 8388608);             // 1024 floats
    float* cpart    = (float*)(ws + 8392704);             // 16*64 floats
    float* ssep     = (float*)(ws + 8396800);             // 512 floats
    unsigned int* counter = (unsigned int*)(ws + 8398848);

    k_pre  <<<404, 256, 0, stream>>>(z_, conv_w, conv_b, wz, emb, out_samp, enorm, cpart, counter);
    k_dist <<<512, 256, 0, stream>>>(wz, emb, enorm, cpart, out_idx, out_samp, out_zq, ssep, out_loss, counter);
}

// Round 5
// 169.252 us; speedup vs baseline: 1.0950x; 1.0950x over previous
//
#include <hip/hip_runtime.h>

// Problem constants
#define BATCH   32
#define CIN     256
#define COUT    64
#define HW      1024          // 32*32
#define NE      1024          // codebook size
#define ED      64            // code dim
#define NROW    32768         // BATCH*COUT*HW/ED
#define ZTOT    2097152       // BATCH*COUT*HW

// d_out layout (floats): z_q_st[ZTOT], loss[1], sampled[32768], min_idx[32768]
#define OFF_LOSS 2097152
#define OFF_SAMP 2097153
#define OFF_IDX  2129921

// LDS strides (floats). k-major layouts, stride%32==4: measured conflict-free
// in R0/R1 for both the transposed-gather staging and the along-row b128 reads.
#define CXSTR 68    // conv Xs/Ws [64 c][64 + 4]
#define ZKSTR 68    // dist zs [64 k][64 row + 4]
#define EKSTR 260   // dist es [32 k][256 code + 4]  (half-K slice)

// ---------------------------------------------------------------------------
// k_pre: fused prep. Conv blocks FIRST (critical path), then zeroing/norms.
// blocks 0..511   : conv, 64-px tile (R1's proven shape: 4px x 4o per thread)
// blocks 512..639 : zero out_samp (block 512 also zeroes the done-counter)
// blocks 640..655 : contrast partials (block-local inv-norms)
// blocks 656..659 : enorm
__global__ __launch_bounds__(256, 4) void k_pre(const float* __restrict__ x,
                                                const float* __restrict__ w,
                                                const float* __restrict__ bias,
                                                float* __restrict__ z,
                                                const float* __restrict__ emb,
                                                float* __restrict__ out_samp,
                                                float* __restrict__ enorm,
                                                float* __restrict__ cpart,
                                                unsigned int* __restrict__ counter) {
    __shared__ float SH[64 * CXSTR * 2];    // 34.8 KB, aliased per branch
    int bx = blockIdx.x;
    int t  = threadIdx.x;

    if (bx < 512) {                       // ---- conv (R1-proven tiling)
        float* Xs = SH;                   // [64 c][CXSTR]
        float* Ws = SH + 64 * CXSTR;      // [64 c][CXSTR]
        int b  = bx >> 4;                 // 0..31
        int p0 = (bx & 15) * 64;          // 0..960
        int pg = t & 15;                  // px: 4*pg + i
        int og = t >> 4;                  // o : 4*og + j
        float acc[4][4];
        #pragma unroll
        for (int i = 0; i < 4; i++)
            #pragma unroll
            for (int j = 0; j < 4; j++) acc[i][j] = 0.0f;

        for (int c0 = 0; c0 < CIN; c0 += 64) {
            __syncthreads();
            {
                int u = t & 15, cg2 = t >> 4;
                #pragma unroll
                for (int m = 0; m < 4; m++) {
                    int c = cg2 + 16 * m;
                    float4 v = *(const float4*)&x[(size_t)(b * CIN + c0 + c) * HW + p0 + 4 * u];
                    *(float4*)&Xs[c * CXSTR + 4 * u] = v;
                }
                #pragma unroll
                for (int m = 0; m < 4; m++) {
                    int o = cg2 + 16 * m;
                    float4 v = *(const float4*)&w[o * CIN + c0 + 4 * u];
                    Ws[(4 * u + 0) * CXSTR + o] = v.x;
                    Ws[(4 * u + 1) * CXSTR + o] = v.y;
                    Ws[(4 * u + 2) * CXSTR + o] = v.z;
                    Ws[(4 * u + 3) * CXSTR + o] = v.w;
                }
            }
            __syncthreads();
            #pragma unroll 8
            for (int k = 0; k < 64; k++) {
                float4 xv = *(const float4*)&Xs[k * CXSTR + 4 * pg];
                float4 wv = *(const float4*)&Ws[k * CXSTR + 4 * og];
                float xa[4] = {xv.x, xv.y, xv.z, xv.w};
                float wb[4] = {wv.x, wv.y, wv.z, wv.w};
                #pragma unroll
                for (int i = 0; i < 4; i++)
                    #pragma unroll
                    for (int j = 0; j < 4; j++)
                        acc[i][j] = fmaf(xa[i], wb[j], acc[i][j]);
            }
        }
        #pragma unroll
        for (int j = 0; j < 4; j++) {
            int o = 4 * og + j;
            float bv = bias[o];
            float4 out;
            out.x = acc[0][j] + bv;
            out.y = acc[1][j] + bv;
            out.z = acc[2][j] + bv;
            out.w = acc[3][j] + bv;
            *(float4*)&z[(size_t)(b * COUT + o) * HW + p0 + 4 * pg] = out;
        }
        return;
    }
    if (bx < 640) {                       // ---- zero sampled
        if (bx == 512 && t == 0) *counter = 0u;
        out_samp[(bx - 512) * 256 + t] = 0.0f;
        return;
    }
    if (bx < 656) {                       // ---- contrast partial (16 blocks)
        float* invl = SH;                 // [64]
        float* S    = SH + 64;            // [256]
        int b2 = bx - 640;
        int i0 = b2 * 64;
        if (t < 64) {
            const float* e = emb + (size_t)(i0 + t) * ED;
            float r8[8];
            #pragma unroll
            for (int s = 0; s < 8; s++) { float xx = e[s]; r8[s] = xx * xx; }
            #pragma unroll
            for (int m = 1; m < 8; m++) {
                #pragma unroll
                for (int s = 0; s < 8; s++) { float xx = e[8 * m + s]; r8[s] += xx * xx; }
            }
            float en = ((r8[0] + r8[1]) + (r8[2] + r8[3])) + ((r8[4] + r8[5]) + (r8[6] + r8[7]));
            invl[t] = 1.0f / sqrtf(en);
        }
        __syncthreads();
        int d = t & 63, q = t >> 6;
        float s = 0.0f;
        #pragma unroll
        for (int m = 0; m < 16; m++) {
            int il = q + 4 * m;
            s = fmaf(emb[(size_t)(i0 + il) * ED + d], invl[il], s);
        }
        S[t] = s;
        __syncthreads();
        if (t < 64)
            cpart[b2 * 64 + t] = (S[t] + S[t + 64]) + (S[t + 128] + S[t + 192]);
        return;
    }
    {                                     // ---- enorm (4 blocks: 656..659)
        int j = (bx - 656) * 256 + t;     // 0..1023
        const float* e = emb + (size_t)j * ED;
        float r8[8];
        #pragma unroll
        for (int s = 0; s < 8; s++) { float xx = e[s]; r8[s] = xx * xx; }
        #pragma unroll
        for (int m = 1; m < 8; m++) {
            #pragma unroll
            for (int s = 0; s < 8; s++) { float xx = e[8 * m + s]; r8[s] += xx * xx; }
        }
        enorm[j] = ((r8[0] + r8[1]) + (r8[2] + r8[3])) + ((r8[4] + r8[5]) + (r8[6] + r8[7]));
    }
}

// ---------------------------------------------------------------------------
// k_dist v5: 512 blocks x 256 threads (8 waves/CU, the only proven-fast
// regime), 64 rows/block, per-thread tile 8 rows x 8 codes (half v0's LDS
// reads per FMA). LDS fits 2 blocks/CU via half-K es slices in v0's
// conflict-free k-major layout: zs[64k][64r] + es[32k][256c] ~= 52 KB.
// Working set acc[64] + 4 float4 -> ~90 VGPR, no spill (R4's spill fixed).
// Per (row,code): one k-ascending fmaf chain across both k-halves ->
// bit-identical distances; argmin scan asc + strict < + jj<bj tie-break.
// Last block folds the loss reduction (same trees as R0's k_final).
__global__ __launch_bounds__(256, 2) void k_dist(const float* __restrict__ z,
                                                 const float* __restrict__ emb,
                                                 const float* __restrict__ enorm,
                                                 const float* __restrict__ cpart,
                                                 float* __restrict__ out_idx,
                                                 float* __restrict__ out_samp,
                                                 float* __restrict__ out_zq,
                                                 float* __restrict__ ssep,
                                                 float* __restrict__ out_loss,
                                                 unsigned int* __restrict__ counter) {
    __shared__ float zs[64 * ZKSTR];      // [k][row]   17.4 KB
    __shared__ float es[32 * EKSTR];      // [k][code]  33.3 KB (reused as scratch)
    __shared__ float zn_s[64];
    __shared__ float en_s[256];
    __shared__ float warr[4];
    __shared__ int   lastflag;
    __shared__ float CS;
    float* redd_s = es;                   // [32][64] floats (post-compute overlay)
    int*   redj_s = (int*)(es + 2048);    // [32][64] ints
    int*   bj_s   = (int*)(es + 4096);    // [64]
    int t = threadIdx.x;
    int row0 = blockIdx.x * 64;
    int rg = t & 7;      // rows  8*rg + i   (i=0..7)
    int cg = t >> 3;     // codes 8*cg + j   (j=0..7, local in 256-chunk)

    // stage zs transposed (v0's exact conflict-free pattern): zs[k][r]
    {
        int k = t & 63, wv = t >> 6;
        #pragma unroll
        for (int m = 0; m < 4; m++) {
            int v = wv + 4 * m;           // 0..15
            float4 val;
            val.x = z[(size_t)(row0 + 4 * v + 0) * ED + k];
            val.y = z[(size_t)(row0 + 4 * v + 1) * ED + k];
            val.z = z[(size_t)(row0 + 4 * v + 2) * ED + k];
            val.w = z[(size_t)(row0 + 4 * v + 3) * ED + k];
            *(float4*)&zs[k * ZKSTR + 4 * v] = val;
        }
    }
    // zn: numpy-pairwise sum of squares per row (global reads, v0 exact)
    if (t < 64) {
        const float* zr = z + (size_t)(row0 + t) * ED;
        float r8[8];
        #pragma unroll
        for (int s = 0; s < 8; s++) { float xx = zr[s]; r8[s] = xx * xx; }
        #pragma unroll
        for (int m = 1; m < 8; m++) {
            #pragma unroll
            for (int s = 0; s < 8; s++) { float xx = zr[8 * m + s]; r8[s] += xx * xx; }
        }
        zn_s[t] = ((r8[0] + r8[1]) + (r8[2] + r8[3])) + ((r8[4] + r8[5]) + (r8[6] + r8[7]));
    }

    float bestd[8];
    int   bestj[8];
    #pragma unroll
    for (int i = 0; i < 8; i++) { bestd[i] = __builtin_huge_valf(); bestj[i] = 0; }

    for (int ch = 0; ch < 4; ch++) {
        int c0 = ch * 256;
        float acc[8][8];
        #pragma unroll
        for (int i = 0; i < 8; i++)
            #pragma unroll
            for (int j = 0; j < 8; j++) acc[i][j] = 0.0f;

        for (int kh = 0; kh < 2; kh++) {
            int kb = kh * 32;
            __syncthreads();   // protect es/en_s from prior readers (covers zn_s/zs at first iter)
            {
                // stage es[kk][256 codes] for kk = kb..kb+31 (transposed gather,
                // v0 pattern; lanes k=0..31 read 128B-contiguous emb columns)
                int k = t & 31, wv = t >> 5;      // wv 0..7
                #pragma unroll
                for (int m = 0; m < 8; m++) {
                    int v = wv + 8 * m;           // 0..63
                    float4 val;
                    val.x = emb[(size_t)(c0 + 4 * v + 0) * ED + kb + k];
                    val.y = emb[(size_t)(c0 + 4 * v + 1) * ED + kb + k];
                    val.z = emb[(size_t)(c0 + 4 * v + 2) * ED + kb + k];
                    val.w = emb[(size_t)(c0 + 4 * v + 3) * ED + kb + k];
                    *(float4*)&es[k * EKSTR + 4 * v] = val;
                }
                if (kh == 0 && t < 64) {
                    float4 ev = *(const float4*)&enorm[c0 + 4 * t];
                    *(float4*)&en_s[4 * t] = ev;
                }
            }
            __syncthreads();

            #pragma unroll 4
            for (int kk = 0; kk < 32; kk++) {
                float4 za0 = *(const float4*)&zs[(kb + kk) * ZKSTR + 8 * rg];
                float4 za1 = *(const float4*)&zs[(kb + kk) * ZKSTR + 8 * rg + 4];
                float4 eb0 = *(const float4*)&es[kk * EKSTR + 8 * cg];
                float4 eb1 = *(const float4*)&es[kk * EKSTR + 8 * cg + 4];
                float xa[8] = {za0.x, za0.y, za0.z, za0.w, za1.x, za1.y, za1.z, za1.w};
                float eb[8] = {eb0.x, eb0.y, eb0.z, eb0.w, eb1.x, eb1.y, eb1.z, eb1.w};
                #pragma unroll
                for (int i = 0; i < 8; i++)
                    #pragma unroll
                    for (int j = 0; j < 8; j++)
                        acc[i][j] = fmaf(xa[i], eb[j], acc[i][j]);
            }
        }

        // epilogue: d = fl(fl(zn + en) - 2*dot); strict < keeps first index
        #pragma unroll
        for (int i = 0; i < 8; i++) {
            float zn = zn_s[8 * rg + i];
            #pragma unroll
            for (int j = 0; j < 8; j++) {
                int cl = 8 * cg + j;
                float A = zn + en_s[cl];
                float D = A - 2.0f * acc[i][j];
                if (D < bestd[i]) { bestd[i] = D; bestj[i] = c0 + cl; }
            }
        }
    }

    __syncthreads();   // es dead; safe to overlay argmin scratch
    #pragma unroll
    for (int i = 0; i < 8; i++) {
        int rl = 8 * rg + i;
        redd_s[cg * 64 + rl] = bestd[i];
        redj_s[cg * 64 + rl] = bestj[i];
    }
    __syncthreads();
    if (t < 64) {
        float bd = __builtin_huge_valf();
        int   bj = 0x7fffffff;
        #pragma unroll
        for (int c = 0; c < 32; c++) {
            float dd = redd_s[c * 64 + t];
            int   jj = redj_s[c * 64 + t];
            if (dd < bd || (dd == bd && jj < bj)) { bd = dd; bj = jj; }
        }
        int rowg = row0 + t;
        bj_s[t]       = bj;
        out_idx[rowg] = (float)bj;              // min_idx as float
        atomicExch(&out_samp[bj], 1.0f);        // scattered, low contention
    }
    __syncthreads();

    // Fused STE epilogue (v0 exact): z from zs (bit-exact), emb gather, SSE.
    // thread t: row r = t&63, k-range [16*kq, 16*kq+16)
    {
        int r  = t & 63;
        int kq = t >> 6;
        int bj = bj_s[r];
        const float* er = emb + (size_t)bj * ED + kq * 16;
        float sq = 0.0f;
        #pragma unroll
        for (int m = 0; m < 4; m++) {
            float4 ev = *(const float4*)&er[4 * m];
            int kk = kq * 16 + 4 * m;
            float zv0 = zs[(kk + 0) * ZKSTR + r];
            float zv1 = zs[(kk + 1) * ZKSTR + r];
            float zv2 = zs[(kk + 2) * ZKSTR + r];
            float zv3 = zs[(kk + 3) * ZKSTR + r];
            float d0 = ev.x - zv0, d1 = ev.y - zv1, d2 = ev.z - zv2, d3 = ev.w - zv3;
            float4 o4;
            o4.x = zv0 + d0; o4.y = zv1 + d1; o4.z = zv2 + d2; o4.w = zv3 + d3;
            *(float4*)&out_zq[(size_t)(row0 + r) * ED + kk] = o4;
            sq += d0 * d0; sq += d1 * d1; sq += d2 * d2; sq += d3 * d3;
        }
        #pragma unroll
        for (int off = 32; off > 0; off >>= 1) sq += __shfl_down(sq, off, 64);
        if ((t & 63) == 0) warr[t >> 6] = sq;
    }
    __syncthreads();

    // Last-block loss reduction: release-fence + counter (512 blocks).
    if (t == 0) {
        ssep[blockIdx.x] = (warr[0] + warr[1]) + (warr[2] + warr[3]);
        __threadfence();                       // make ssep visible device-wide
        unsigned int old = atomicAdd(counter, 1u);
        lastflag = (old == 511u) ? 1 : 0;
    }
    __syncthreads();
    if (lastflag) {
        __threadfence();                       // acquire: see all blocks' ssep
        double* SD = (double*)es;              // es scratch dead; 2 KB
        const volatile float* sv = (const volatile float*)ssep;
        SD[t] = (double)sv[t] + (double)sv[t + 256];
        __syncthreads();
        #pragma unroll
        for (int off = 128; off > 0; off >>= 1) {
            if (t < off) SD[t] += SD[t + off];
            __syncthreads();
        }
        if (t < 64) {
            float v = 0.0f;
            #pragma unroll
            for (int m = 0; m < 16; m++) v += cpart[m * 64 + t];
            float sq = v * v;
            #pragma unroll
            for (int off = 32; off > 0; off >>= 1) sq += __shfl_down(sq, off, 64);
            if (t == 0) CS = sq / (1024.0f * 1024.0f);
        }
        __syncthreads();
        if (t == 0) {
            float m = (float)(SD[0] / (double)ZTOT);
            float loss = m + 0.25f * m;        // LEGACY: mse + BETA*mse
            out_loss[0] = loss + CS;
        }
    }
}

// ---------------------------------------------------------------------------
extern "C" void kernel_launch(void* const* d_in, const int* in_sizes, int n_in,
                              void* d_out, int out_size, void* d_ws, size_t ws_size,
                              hipStream_t stream) {
    (void)in_sizes; (void)n_in; (void)out_size; (void)ws_size;
    const float* z_     = (const float*)d_in[0];
    const float* conv_w = (const float*)d_in[1];
    const float* conv_b = (const float*)d_in[2];
    const float* emb    = (const float*)d_in[3];

    float* out      = (float*)d_out;
    float* out_zq   = out;
    float* out_loss = out + OFF_LOSS;
    float* out_samp = out + OFF_SAMP;
    float* out_idx  = out + OFF_IDX;

    char*  ws       = (char*)d_ws;
    float* wz       = (float*)ws;                         // 2M floats (8 MB)
    float* enorm    = (float*)(ws + 8388608);             // 1024 floats
    float* cpart    = (float*)(ws + 8392704);             // 16*64 floats
    float* ssep     = (float*)(ws + 8396800);             // 512 floats
    unsigned int* counter = (unsigned int*)(ws + 8398848);

    k_pre  <<<660, 256, 0, stream>>>(z_, conv_w, conv_b, wz, emb, out_samp, enorm, cpart, counter);
    k_dist <<<512, 256, 0, stream>>>(wz, emb, enorm, cpart, out_idx, out_samp, out_zq, ssep, out_loss, counter);
}